// Round 1
// baseline (143.900 us; speedup 1.0000x reference)
//
#include <hip/hip_runtime.h>
#include <math.h>

#define NQ 12
#define DIM 4096
#define KS 6
#define BB 256
#define SEQ 128
#define DEMB 512

// v2: 1024 threads (16 waves), 4 amps/thread.
// R0 counters: VALUBusy 31%, Occupancy 21.5% (= one 512-thr block/CU,
// 2 waves/SIMD), all throughput floors >=3x under dur -> latency-bound.
// Double TLP: 6 phases x 2 wires, 6 trips/step (4 intra-wave fences +
// 2 barriers, same barrier count as v1), triple-buffered LDS (96KB state).
//
// Layouts (j = 12-bit state index, wire w <-> bit 11-w):
//  L_A: r=j[1:0]   lane=j[7:2]            wave=j[11:8]
//  L_B: r=j[3:2]   lane={j[7:4],j[1:0]}   wave=j[11:8]
//  L_C: r=j[5:4]   lane={j[7:6],j[3:0]}   wave=j[11:8]
//  L_D: r=j[7:6]   lane=j[5:0]            wave=j[11:8]
//  L_E: r=j[9:8]   lane={j[11:10],j[3:0]} wave=j[7:4]
//  L_F: r=j[11:10] lane={j[9:8],j[3:0]}   wave=j[7:4]
// Trips: A->B,B->C,C->D intra-wave (buf0, fence only); D->E cross (buf0,
// barrier B1); E->F intra (buf1, fence); ring-folded F->A' cross (buf2, B2).
// Expvals PRE-ring in L_F via prefix-XOR parity strings (Walsh chains).

#define RG(P, W) { \
    float4 c0 = *(const float4*)&s_u[k][W][0]; \
    float4 c1 = *(const float4*)&s_u[k][W][4]; \
    float u00r=c0.x,u00i=c0.y,u01r=c0.z,u01i=c0.w; \
    float u10r=c1.x,u10i=c1.y,u11r=c1.z,u11i=c1.w; \
    _Pragma("unroll") \
    for (int r0 = 0; r0 < 4; ++r0) if (!(r0 & (1 << (P)))) { \
        int r1 = r0 | (1 << (P)); \
        float2 A = a[r0], Bv = a[r1]; \
        a[r0].x = u00r*A.x - u00i*A.y + u01r*Bv.x - u01i*Bv.y; \
        a[r0].y = u00r*A.y + u00i*A.x + u01r*Bv.y + u01i*Bv.x; \
        a[r1].x = u10r*A.x - u10i*A.y + u11r*Bv.x - u11i*Bv.y; \
        a[r1].y = u10r*A.y + u10i*A.x + u11r*Bv.y + u11i*Bv.x; \
    } }

#define BF_PLAIN(v, m) { float p_ = __shfl_xor(v, m, 64); v = v + p_; }
#define BF_SIGN(v, m)  { float p_ = __shfl_xor(v, m, 64); float d_ = v - p_; \
                         v = (lane & m) ? -d_ : d_; }

// wave-local LDS write->read ordering (no block barrier)
#define WAVE_FENCE() asm volatile("s_waitcnt lgkmcnt(0)" ::: "memory")

__device__ __forceinline__ int swz14(int x) { return x ^ ((x >> 4) & 14); }

__global__ __launch_bounds__(1024) void fused_kernel(
    const int* __restrict__ ids, const int* __restrict__ mask,
    const float* __restrict__ emb, const float* __restrict__ pw,
    const float* __restrict__ pb, const float* __restrict__ theta,
    const float* __restrict__ hw, const float* __restrict__ hb,
    float* __restrict__ readouts, float* __restrict__ logits,
    float* __restrict__ last)
{
    __shared__ __align__(16) float2 buf0[DIM];   // 32 KB (trips A-D)
    __shared__ __align__(16) float2 buf1[DIM];   // 32 KB (trip E->F / enc ids)
    __shared__ __align__(16) float2 buf2[DIM];   // 32 KB (ring scatter)
    __shared__ __align__(16) float  s_u[KS][NQ][8];
    __shared__ float  s_red[16][NQ];
    __shared__ float  s_msum[8];
    __shared__ float  s_wred[2][NQ];
    __shared__ float  s_x[NQ];
    __shared__ float  s_hw[8 * NQ];
    __shared__ float  s_hb[8];

    int b = blockIdx.x;
    int tid = threadIdx.x;
    int lane = tid & 63, wave = tid >> 6;     // wave 0..15

    // ---------------- encoder ----------------
    int*   s_ids = (int*)buf1;
    float* s_m   = (float*)buf1 + SEQ;
    float4* s_part = (float4*)buf0;           // [8][128]

    if (tid < SEQ) {
        s_ids[tid] = ids[b * SEQ + tid];
        s_m[tid]   = (float)mask[b * SEQ + tid];
    }
    if (tid >= 256 && tid < 256 + 8 * NQ) s_hw[tid - 256] = hw[tid - 256];
    if (tid >= 384 && tid < 392)          s_hb[tid - 384] = hb[tid - 384];
    __syncthreads();

    {
        int g = tid >> 7, e = tid & 127;      // g 0..7
        float4 acc = make_float4(0.f, 0.f, 0.f, 0.f);
        float msum = 0.f;
        #pragma unroll 4
        for (int s = g; s < SEQ; s += 8) {
            float m = s_m[s];
            float4 v = ((const float4*)emb)[(size_t)s_ids[s] * 128 + e];
            acc.x = fmaf(m, v.x, acc.x);
            acc.y = fmaf(m, v.y, acc.y);
            acc.z = fmaf(m, v.z, acc.z);
            acc.w = fmaf(m, v.w, acc.w);
            msum += m;
        }
        __syncthreads();   // ids/m reads done before buf0 overlay write
        s_part[g * 128 + e] = acc;
        if (e == 0) s_msum[g] = msum;
    }
    __syncthreads();

    if (tid < 128) {
        float tm = s_msum[0] + s_msum[1] + s_msum[2] + s_msum[3]
                 + s_msum[4] + s_msum[5] + s_msum[6] + s_msum[7];
        tm = fmaxf(tm, 1.f);
        float inv = 1.f / tm;
        float4 p = make_float4(0.f, 0.f, 0.f, 0.f);
        #pragma unroll
        for (int g = 0; g < 8; ++g) {
            float4 pg = s_part[g * 128 + tid];
            p.x += pg.x; p.y += pg.y; p.z += pg.z; p.w += pg.w;
        }
        p.x *= inv; p.y *= inv; p.z *= inv; p.w *= inv;
        float z[NQ];
        #pragma unroll
        for (int i = 0; i < NQ; ++i) {
            float4 w4 = ((const float4*)pw)[i * 128 + tid];
            z[i] = p.x * w4.x + p.y * w4.y + p.z * w4.z + p.w * w4.w;
        }
        #pragma unroll
        for (int i = 0; i < NQ; ++i) {
            #pragma unroll
            for (int off = 32; off > 0; off >>= 1)
                z[i] += __shfl_xor(z[i], off, 64);
        }
        if ((tid & 63) == 0) {
            int w = tid >> 6;
            #pragma unroll
            for (int i = 0; i < NQ; ++i) s_wred[w][i] = z[i];
        }
    }
    __syncthreads();
    if (tid < NQ) {
        float d = pb[tid] + s_wred[0][tid] + s_wred[1][tid];
        s_x[tid] = tanhf(d) * 3.14159274101257324f;
    }
    __syncthreads();

    // ---------------- gate matrices: U = Rot(phi,te,om) @ RY(x) ----------
    if (tid < KS * NQ) {
        int k = tid / NQ, w = tid % NQ;
        float ang = s_x[w];
        float cy = cosf(0.5f * ang), sy = sinf(0.5f * ang);
        const float* th = theta + (k * NQ + w) * 3;
        float phi = th[0], te = th[1], om = th[2];
        float ct = cosf(0.5f * te), st = sinf(0.5f * te);
        float a1 = -0.5f * (phi + om);
        float epr = cosf(a1), epi = sinf(a1);
        float a2 = 0.5f * (phi - om);
        float emr = cosf(a2), emi = sinf(a2);
        float R00r = epr * ct,  R00i = epi * ct;
        float R01r = -emr * st, R01i = -emi * st;
        float R10r = emr * st,  R10i = -emi * st;
        float R11r = epr * ct,  R11i = -epi * ct;
        s_u[k][w][0] =  R00r * cy + R01r * sy;
        s_u[k][w][1] =  R00i * cy + R01i * sy;
        s_u[k][w][2] = -R00r * sy + R01r * cy;
        s_u[k][w][3] = -R00i * sy + R01i * cy;
        s_u[k][w][4] =  R10r * cy + R11r * sy;
        s_u[k][w][5] =  R10i * cy + R11i * sy;
        s_u[k][w][6] = -R10r * sy + R11r * cy;
        s_u[k][w][7] = -R10i * sy + R11i * cy;
    }

    // ---------------- constant addresses ----------------
    int T4 = tid << 2;                 // L_A base logical index (4 amps)
    int bA4 = swz14(T4) >> 1;          // float4 idx; partner at bA4^1
    int aB[4], aC[4], aD[4], aE[4], aF[4], idxP[4];
    #pragma unroll
    for (int r = 0; r < 4; ++r) {
        aB[r] = swz14((wave << 8) | ((lane >> 2) << 4) | (r << 2) | (lane & 3));
        aC[r] = swz14((wave << 8) | ((lane >> 4) << 6) | (r << 4) | (lane & 15));
        aD[r] = swz14((wave << 8) | (r << 6) | lane);
        aE[r] = swz14(((lane >> 4) << 10) | (r << 8) | (wave << 4) | (lane & 15));
        int jF = (r << 10) | ((lane >> 4) << 8) | (wave << 4) | (lane & 15);
        aF[r] = swz14(jF);
        // ring CNOT permutation (prefix-XOR), verified in prior session (R6)
        int b0 = (jF >> 11) & 1;
        int pref = b0, outv = 0;
        for (int w = 1; w < NQ; ++w) {
            pref ^= (jF >> (11 - w)) & 1;
            outv |= pref << (11 - w);
        }
        outv |= (b0 ^ pref) << 11;
        idxP[r] = swz14(outv);
    }
    // wave-bit (j[7:4]) sign parities for expvals
    int s3v   = (wave >> 3) & 1;               // j[7]   (wire 4)
    int s32v  = s3v ^ ((wave >> 2) & 1);       // j[7:6]
    int s321v = s32v ^ ((wave >> 1) & 1);      // j[7:5]
    int sallv = s321v ^ (wave & 1);            // j[7:4]

    float2 a[4];
    #pragma unroll
    for (int r = 0; r < 4; ++r) a[r] = make_float2(0.f, 0.f);
    if (tid == 0) a[0].x = 1.f;     // |0...0>: j=0 -> wave0,lane0,r0
    __syncthreads();   // s_u ready, enc buf reads done

    // ---------------- K steps ----------------
    for (int k = 0; k < KS; ++k) {
        // phase A (L_A): wires 11,10
        RG(0, 11) RG(1, 10)

        // trip 1 (intra-wave): b128 dump -> gather L_B
        #pragma unroll
        for (int i = 0; i < 2; ++i)
            ((float4*)buf0)[bA4 ^ i] =
                make_float4(a[2*i].x, a[2*i].y, a[2*i+1].x, a[2*i+1].y);
        WAVE_FENCE();
        #pragma unroll
        for (int r = 0; r < 4; ++r) a[r] = buf0[aB[r]];

        // phase B: wires 9,8
        RG(0, 9) RG(1, 8)

        // trip 2 (intra-wave): dump L_B -> gather L_C
        #pragma unroll
        for (int r = 0; r < 4; ++r) buf0[aB[r]] = a[r];
        WAVE_FENCE();
        #pragma unroll
        for (int r = 0; r < 4; ++r) a[r] = buf0[aC[r]];

        // phase C: wires 7,6
        RG(0, 7) RG(1, 6)

        // trip 3 (intra-wave): dump L_C -> gather L_D
        #pragma unroll
        for (int r = 0; r < 4; ++r) buf0[aC[r]] = a[r];
        WAVE_FENCE();
        #pragma unroll
        for (int r = 0; r < 4; ++r) a[r] = buf0[aD[r]];

        // phase D: wires 5,4
        RG(0, 5) RG(1, 4)

        // trip 4 (cross-wave): dump L_D -> barrier -> gather L_E
        #pragma unroll
        for (int r = 0; r < 4; ++r) buf0[aD[r]] = a[r];
        __syncthreads();                                   // B1
        #pragma unroll
        for (int r = 0; r < 4; ++r) a[r] = buf0[aE[r]];

        // phase E: wires 3,2
        RG(0, 3) RG(1, 2)

        // trip 5 (intra-wave, buf1): dump L_E -> gather L_F
        #pragma unroll
        for (int r = 0; r < 4; ++r) buf1[aE[r]] = a[r];
        WAVE_FENCE();
        #pragma unroll
        for (int r = 0; r < 4; ++r) a[r] = buf1[aF[r]];

        // phase F: wires 1,0
        RG(0, 1) RG(1, 0)

        // ring scatter FIRST (drains while expvals shuffle), into buf2
        #pragma unroll
        for (int r = 0; r < 4; ++r) buf2[idxP[r]] = a[r];

        // expvals PRE-ring in L_F: post-ring <Z_w> = prefix parity strings.
        // In-thread over r=j[11:10]; lane signs l5..l0 = j[9],j[8],j[3..0];
        // wave signs j[7:4] applied at s_red write.
        {
            float p0 = a[0].x*a[0].x + a[0].y*a[0].y;
            float p1 = a[1].x*a[1].x + a[1].y*a[1].y;
            float p2 = a[2].x*a[2].x + a[2].y*a[2].y;
            float p3 = a[3].x*a[3].x + a[3].y*a[3].y;
            float T1v = (p0 + p3) - (p1 + p2);   // (-1)^(j11^j10)
            float T0v = (p0 + p2) - (p1 + p3);   // (-1)^(j10)

            float v1 = T1v;                       // wire 1: parity j[11:10]
            BF_PLAIN(v1,32) BF_PLAIN(v1,16) BF_PLAIN(v1,8)
            BF_PLAIN(v1,4)  BF_PLAIN(v1,2)  BF_PLAIN(v1,1)

            float c = T1v;
            BF_SIGN(c,32);                        // +j[9]
            float w2v = c; BF_PLAIN(w2v,16) BF_PLAIN(w2v,8) BF_PLAIN(w2v,4)
                           BF_PLAIN(w2v,2)  BF_PLAIN(w2v,1)
            BF_SIGN(c,16);                        // +j[8]
            float w3v = c; BF_PLAIN(w3v,8) BF_PLAIN(w3v,4)
                           BF_PLAIN(w3v,2) BF_PLAIN(w3v,1)
            BF_SIGN(c,8);                         // +j[3]
            float w8v = c; BF_PLAIN(w8v,4) BF_PLAIN(w8v,2) BF_PLAIN(w8v,1)
            BF_SIGN(c,4);                         // +j[2]
            float w9v = c; BF_PLAIN(w9v,2) BF_PLAIN(w9v,1)
            BF_SIGN(c,2);                         // +j[1]
            float w10v = c; BF_PLAIN(w10v,1)
            BF_SIGN(c,1);                         // +j[0]  -> wire 11 lane part

            float q0 = T0v;                       // wire 0: parity j[10:0]
            BF_SIGN(q0,32) BF_SIGN(q0,16) BF_SIGN(q0,8)
            BF_SIGN(q0,4)  BF_SIGN(q0,2)  BF_SIGN(q0,1)

            if (lane == 0) {
                float* sr = s_red[wave];
                sr[0]  = sallv ? -q0   : q0;
                sr[1]  = v1;
                sr[2]  = w2v;
                sr[3]  = w3v;
                sr[4]  = s3v   ? -w3v  : w3v;
                sr[5]  = s32v  ? -w3v  : w3v;
                sr[6]  = s321v ? -w3v  : w3v;
                sr[7]  = sallv ? -w3v  : w3v;
                sr[8]  = sallv ? -w8v  : w8v;
                sr[9]  = sallv ? -w9v  : w9v;
                sr[10] = sallv ? -w10v : w10v;
                sr[11] = sallv ? -c    : c;
            }
        }

        __syncthreads();                                   // B2
        #pragma unroll
        for (int i = 0; i < 2; ++i) {
            float4 v = ((float4*)buf2)[bA4 ^ i];
            a[2*i]   = make_float2(v.x, v.y);
            a[2*i+1] = make_float2(v.z, v.w);
        }

        // finalize readouts + head (overlaps next step's phase-A gates)
        if (tid < NQ) {
            float s = 0.f;
            #pragma unroll
            for (int w2 = 0; w2 < 16; ++w2) s += s_red[w2][tid];
            readouts[(k * BB + b) * NQ + tid] = s;
        }
        if (tid < 8) {
            float acc2 = s_hb[tid];
            #pragma unroll
            for (int i = 0; i < NQ; ++i) {
                float si = 0.f;
                #pragma unroll
                for (int w2 = 0; w2 < 16; ++w2) si += s_red[w2][i];
                acc2 = fmaf(si, s_hw[tid * NQ + i], acc2);
            }
            logits[(k * BB + b) * 8 + tid] = acc2;
            if (k == KS - 1) last[b * 8 + tid] = acc2;
        }
    }
}

extern "C" void kernel_launch(void* const* d_in, const int* in_sizes, int n_in,
                              void* d_out, int out_size, void* d_ws, size_t ws_size,
                              hipStream_t stream) {
    const int*   ids   = (const int*)d_in[0];
    const int*   mask  = (const int*)d_in[1];
    const float* emb   = (const float*)d_in[2];
    const float* pw    = (const float*)d_in[3];
    const float* pb    = (const float*)d_in[4];
    const float* theta = (const float*)d_in[5];
    const float* hw    = (const float*)d_in[6];
    const float* hb    = (const float*)d_in[7];
    float* out = (float*)d_out;

    float* readouts = out + KS * BB * 8;              // [K,B,NQ]
    float* last     = out + KS * BB * 8 + KS * BB * NQ;

    fused_kernel<<<BB, 1024, 0, stream>>>(ids, mask, emb, pw, pb, theta,
                                          hw, hb, readouts, out, last);
}